// Round 7
// baseline (664.245 us; speedup 1.0000x reference)
//
#include <hip/hip_runtime.h>
#include <hip/hip_cooperative_groups.h>

namespace cg = cooperative_groups;

#define TPB 256
#define SORTBLKS 1024     // 4 blocks/CU, co-resident for cooperative launch
#define BSH 8             // dst >> 8 -> bucket; 256 dsts per bucket

typedef __attribute__((ext_vector_type(4))) float f32x4;
typedef __attribute__((ext_vector_type(8))) short short8;

__device__ __forceinline__ unsigned short f2bf(float f) {
    unsigned u = __float_as_uint(f);
    u = (u + 0x7fffu + ((u >> 16) & 1u)) >> 16;
    return (unsigned short)u;
}
__device__ __forceinline__ float bflo(unsigned u) { return __uint_as_float(u << 16); }
__device__ __forceinline__ float bfhi(unsigned u) { return __uint_as_float(u & 0xffff0000u); }

// ============ ONE cooperative kernel: zero + castW + hist + scan + scatter + CSR
// Replaces 6 dispatches (memset, bhist, bscan, bscatter, bcsr, castW) with 1.

__global__ __launch_bounds__(256, 4) void k_coopsort(
    const int* __restrict__ src, const int* __restrict__ dst,
    const float* __restrict__ W,
    int* __restrict__ btotal, int* __restrict__ bcur,
    int2* __restrict__ pairs, int* __restrict__ offsets,
    int* __restrict__ sorted_src, float* __restrict__ dinv,
    unsigned short* __restrict__ Wt, int E, int N, int NB)
{
    cg::grid_group grid = cg::this_grid();
    __shared__ int sh[512];
    __shared__ int lbase[512];      // exclusive bucket bases, persists to phase 4
    __shared__ int stmp[2][512];
    __shared__ int hist[256];
    __shared__ int scur[256];

    const int t = threadIdx.x;
    const int nblocks = gridDim.x;
    const long gtid = (long)blockIdx.x * 256 + t;
    const long gsz = (long)nblocks * 256;
    const int chunk = (E + nblocks - 1) / nblocks;
    const int lo = blockIdx.x * chunk;
    const int hi = min(E, lo + chunk);

    // ---- phase 0: zero btotal, cast W -> bf16 Wt, offsets[N]=E ----
    for (long i = gtid; i < NB; i += gsz) btotal[i] = 0;
    for (long i = gtid; i < 128 * 128; i += gsz) Wt[i] = f2bf(W[i]);
    if (gtid == 0) offsets[N] = E;
    grid.sync();

    // ---- phase 1: coarse bucket histogram (LDS-aggregated) ----
    for (int i = t; i < NB; i += 256) sh[i] = 0;
    __syncthreads();
    for (int e = lo + t; e < hi; e += 256) atomicAdd(&sh[dst[e] >> BSH], 1);
    __syncthreads();
    for (int i = t; i < NB; i += 256)
        if (sh[i]) atomicAdd(&btotal[i], sh[i]);   // fire-and-forget
    grid.sync();

    // ---- phase 2: every block scans btotal (512-wide, 2 elems/thread) ----
    {
        int v0 = (t < NB) ? btotal[t] : 0;
        int v1 = (t + 256 < NB) ? btotal[t + 256] : 0;
        stmp[0][t] = v0; stmp[0][t + 256] = v1;
        __syncthreads();
        int sb = 0;
        for (int d = 1; d < 512; d <<= 1) {
            int a = stmp[sb][t]       + ((t       >= d) ? stmp[sb][t - d]       : 0);
            int bv = stmp[sb][t + 256] + ((t + 256 >= d) ? stmp[sb][t + 256 - d] : 0);
            stmp[sb ^ 1][t] = a; stmp[sb ^ 1][t + 256] = bv;
            sb ^= 1;
            __syncthreads();
        }
        lbase[t]       = stmp[sb][t]       - v0;   // exclusive
        lbase[t + 256] = stmp[sb][t + 256] - v1;   // lbase[NB] == E automatically
        __syncthreads();
        if (blockIdx.x == 0) {
            if (t < NB) bcur[t] = lbase[t];
            if (t + 256 < NB) bcur[t + 256] = lbase[t + 256];
        }
    }
    grid.sync();

    // ---- phase 3: scatter edges into bucket regions ----
    for (int i = t; i < NB; i += 256) sh[i] = 0;
    __syncthreads();
    for (int e = lo + t; e < hi; e += 256) atomicAdd(&sh[dst[e] >> BSH], 1);
    __syncthreads();
    for (int i = t; i < NB; i += 256) {       // thread t exclusively owns slots t, t+256
        int c = sh[i];
        sh[i] = c ? atomicAdd(&bcur[i], c) : 0;
    }
    __syncthreads();
    for (int e = lo + t; e < hi; e += 256) {
        int d = dst[e];
        int pos = atomicAdd(&sh[d >> BSH], 1);   // LDS atomic
        pairs[pos] = make_int2(d, src[e]);
    }
    grid.sync();

    // ---- phase 4: per-bucket fine CSR + offsets + dinv ----
    for (int b = blockIdx.x; b < NB; b += nblocks) {
        int s0 = lbase[b];
        int s1 = (b + 1 < 512) ? lbase[b + 1] : E;
        hist[t] = 0;
        __syncthreads();
        for (int e = s0 + t; e < s1; e += 256)
            atomicAdd(&hist[pairs[e].x & 255], 1);
        __syncthreads();
        int v = hist[t];
        stmp[0][t] = v;
        __syncthreads();
        int sb = 0;
        for (int d = 1; d < 256; d <<= 1) {
            int val = stmp[sb][t] + ((t >= d) ? stmp[sb][t - d] : 0);
            stmp[sb ^ 1][t] = val;
            sb ^= 1;
            __syncthreads();
        }
        int gbase = s0 + stmp[sb][t] - v;
        scur[t] = gbase;
        int d = (b << BSH) + t;
        if (d < N) { offsets[d] = gbase; dinv[d] = rsqrtf((float)v + 1.0f); }
        __syncthreads();
        for (int e = s0 + t; e < s1; e += 256) {
            int2 pr = pairs[e];
            int pos = atomicAdd(&scur[pr.x & 255], 1);  // LDS atomic
            sorted_src[pos] = pr.y;
        }
        __syncthreads();
    }
}

// ============ GEMM via MFMA: g[i][j] = bf16( dinv[i] * sum_k x[i][k]*W[j][k] ) ====

__global__ __launch_bounds__(256) void k_gemm(const float* __restrict__ x,
                                              const unsigned short* __restrict__ Wt,
                                              const float* __restrict__ dinv,
                                              unsigned short* __restrict__ g, int n) {
    __shared__ unsigned short wb[128][136];
    const int tid = threadIdx.x;

    for (int chunk = tid; chunk < 2048; chunk += 256) {
        int nrow = chunk >> 4, k8 = (chunk & 15) << 3;
        *(uint4*)&wb[nrow][k8] = ((const uint4*)Wt)[chunk];
    }
    __syncthreads();

    const int lane = tid & 63;
    const int wid  = tid >> 6;
    const int l15  = lane & 15;
    const int quad = lane >> 4;
    const int row  = blockIdx.x * 64 + wid * 16 + l15;
    const int rowc = (row < n) ? row : (n - 1);

    f32x4 acc[8];
    #pragma unroll
    for (int t = 0; t < 8; ++t) acc[t] = (f32x4){0.f, 0.f, 0.f, 0.f};

    #pragma unroll
    for (int ks = 0; ks < 4; ++ks) {
        const int kb = ks * 32 + quad * 8;
        float4 a0 = *(const float4*)(x + (long)rowc * 128 + kb);
        float4 a1 = *(const float4*)(x + (long)rowc * 128 + kb + 4);
        union { unsigned short u[8]; short8 v; } af;
        af.u[0] = f2bf(a0.x); af.u[1] = f2bf(a0.y); af.u[2] = f2bf(a0.z); af.u[3] = f2bf(a0.w);
        af.u[4] = f2bf(a1.x); af.u[5] = f2bf(a1.y); af.u[6] = f2bf(a1.z); af.u[7] = f2bf(a1.w);
        #pragma unroll
        for (int t = 0; t < 8; ++t) {
            short8 bf = *(const short8*)&wb[t * 16 + l15][kb];
            acc[t] = __builtin_amdgcn_mfma_f32_16x16x32_bf16(af.v, bf, acc[t], 0, 0, 0);
        }
    }

    int   orow[4];
    float dv[4];
    #pragma unroll
    for (int r = 0; r < 4; ++r) {
        orow[r] = blockIdx.x * 64 + wid * 16 + quad * 4 + r;
        dv[r]   = (orow[r] < n) ? dinv[orow[r]] : 0.f;
    }
    #pragma unroll
    for (int t = 0; t < 8; ++t) {
        int col = t * 16 + l15;
        #pragma unroll
        for (int r = 0; r < 4; ++r) {
            if (orow[r] < n)
                g[(long)orow[r] * 128 + col] = f2bf(acc[t][r] * dv[r]);
        }
    }
}

// ============ CSR aggregate: out[d] = dinv[d]*(g[d] + sum g[src]) + b ============

__global__ __launch_bounds__(256) void k_aggregate(const int* __restrict__ sorted_src,
                                                   const int* __restrict__ offsets,
                                                   const unsigned short* __restrict__ g,
                                                   const float* __restrict__ dinv,
                                                   const float* __restrict__ b,
                                                   float* __restrict__ out, int n) {
    int d = blockIdx.x * (TPB / 32) + (threadIdx.x >> 5);
    if (d >= n) return;
    int c = (threadIdx.x & 31) << 2;

    int s0 = offsets[d];
    int s1 = offsets[d + 1];

    float4 acc = make_float4(0.f, 0.f, 0.f, 0.f);
    auto addrow = [&](int r) {
        uint2 p = *(const uint2*)(g + (long)r * 128 + c);
        acc.x += bflo(p.x); acc.y += bfhi(p.x);
        acc.z += bflo(p.y); acc.w += bfhi(p.y);
    };

    addrow(d);  // self-loop
    int e = s0;
    for (; e + 8 <= s1; e += 8) {
        int a[8];
        #pragma unroll
        for (int j = 0; j < 8; ++j) a[j] = sorted_src[e + j];
        #pragma unroll
        for (int j = 0; j < 8; ++j) addrow(a[j]);
    }
    for (; e + 4 <= s1; e += 4) {
        int a[4];
        #pragma unroll
        for (int j = 0; j < 4; ++j) a[j] = sorted_src[e + j];
        #pragma unroll
        for (int j = 0; j < 4; ++j) addrow(a[j]);
    }
    for (; e < s1; ++e) addrow(sorted_src[e]);

    float s = dinv[d];
    float4 bb = *(const float4*)(b + c);
    float4 r = make_float4(acc.x * s + bb.x, acc.y * s + bb.y,
                           acc.z * s + bb.z, acc.w * s + bb.w);
    *(float4*)(out + (long)d * 128 + c) = r;
}

// ============ launch ============

extern "C" void kernel_launch(void* const* d_in, const int* in_sizes, int n_in,
                              void* d_out, int out_size, void* d_ws, size_t ws_size,
                              hipStream_t stream) {
    const float* x  = (const float*)d_in[0];
    const int*   ei = (const int*)d_in[1];
    // d_in[2] = edge_attr (unused; GCN edge weight = 1)
    const float* W  = (const float*)d_in[3];
    const float* b  = (const float*)d_in[4];
    float* out = (float*)d_out;

    const int N = in_sizes[0] / 128;
    const int E = in_sizes[1] / 2;
    const int* src = ei;
    const int* dst = ei + E;
    const int NB = (N + 255) >> BSH;   // 391 buckets (<= 511)

    // ---- workspace carve (~45.7 MB) ----
    char* p = (char*)d_ws;
    auto carve = [&](size_t bytes) { char* q = p; p += (bytes + 255) & ~(size_t)255; return q; };
    int*            btotal     = (int*)           carve(512 * 4);
    int*            bcur       = (int*)           carve(512 * 4);
    int*            offsets    = (int*)           carve((size_t)(N + 1) * 4);
    float*          dinv       = (float*)         carve((size_t)N * 4);
    int2*           pairs      = (int2*)          carve((size_t)E * 8);
    int*            sorted_src = (int*)           carve((size_t)E * 4);
    unsigned short* Wt         = (unsigned short*)carve((size_t)128 * 128 * 2);
    unsigned short* g          = (unsigned short*)carve((size_t)N * 128 * 2);

    // cooperative sort: 1024 blocks x 256 thr (4/CU co-resident)
    int Ev = E, Nv = N, NBv = NB;
    void* args[] = {(void*)&src, (void*)&dst, (void*)&W,
                    (void*)&btotal, (void*)&bcur, (void*)&pairs,
                    (void*)&offsets, (void*)&sorted_src, (void*)&dinv,
                    (void*)&Wt, (void*)&Ev, (void*)&Nv, (void*)&NBv};
    hipLaunchCooperativeKernel((const void*)k_coopsort, dim3(SORTBLKS), dim3(TPB),
                               args, 0, stream);

    k_gemm<<<(N + 63) / 64, TPB, 0, stream>>>(x, Wt, dinv, g, N);

    k_aggregate<<<(N + (TPB / 32) - 1) / (TPB / 32), TPB, 0, stream>>>(
        sorted_src, offsets, g, dinv, b, out, N);
}

// Round 8
// 254.932 us; speedup vs baseline: 2.6056x; 2.6056x over previous
//
#include <hip/hip_runtime.h>

#define TPB 256
#define NBLK 256          // blocks for edge-streaming kernels
#define BSH 8             // dst >> 8 -> bucket; 256 dsts per bucket

typedef __attribute__((ext_vector_type(4))) float f32x4;
typedef __attribute__((ext_vector_type(8))) short short8;

__device__ __forceinline__ unsigned short f2bf(float f) {
    unsigned u = __float_as_uint(f);
    u = (u + 0x7fffu + ((u >> 16) & 1u)) >> 16;
    return (unsigned short)u;
}
__device__ __forceinline__ float bflo(unsigned u) { return __uint_as_float(u << 16); }
__device__ __forceinline__ float bfhi(unsigned u) { return __uint_as_float(u & 0xffff0000u); }

// ============ pass A: per-block bucket histogram matrix ============
// Plain stores into blockhist[block][512] -- no global atomics, no memset needed
// (every slot written unconditionally).

__global__ __launch_bounds__(256) void k_bhist(const int* __restrict__ dst,
                                               int* __restrict__ blockhist, int E) {
    __shared__ int sh[512];
    int t = threadIdx.x;
    sh[t] = 0; sh[t + 256] = 0;
    __syncthreads();
    int chunk = (E + NBLK - 1) / NBLK;
    int lo = blockIdx.x * chunk;
    int hi = min(E, lo + chunk);
    for (int e = lo + t; e < hi; e += 256)
        atomicAdd(&sh[dst[e] >> BSH], 1);          // LDS atomic only
    __syncthreads();
    int* row = blockhist + blockIdx.x * 512;
    row[t] = sh[t];
    row[t + 256] = sh[t + 256];
}

// ============ pass B: column-sum + scan (1 block, 512 thr) ============

__global__ __launch_bounds__(512) void k_bscan(const int* __restrict__ blockhist,
                                               int* __restrict__ bbase, int* __restrict__ bcur,
                                               int* __restrict__ offsets, int E, int N) {
    __shared__ int tmp[2][512];
    int t = threadIdx.x;
    int total = 0;
    #pragma unroll 8
    for (int b = 0; b < NBLK; ++b) total += blockhist[b * 512 + t];  // independent, coalesced
    tmp[0][t] = total;
    __syncthreads();
    int sb = 0;
    for (int d = 1; d < 512; d <<= 1) {
        int val = tmp[sb][t] + ((t >= d) ? tmp[sb][t - d] : 0);
        tmp[sb ^ 1][t] = val;
        sb ^= 1;
        __syncthreads();
    }
    int excl = tmp[sb][t] - total;
    bbase[t] = excl;
    bcur[t] = excl;
    if (t == 0) { bbase[512] = E; offsets[N] = E; }
}

// ============ pass C: scatter edges into bucket regions ============
// One returning global atomic per (block,bucket) (~100K total, trivial);
// edge stores land in ~contiguous runs.

__global__ __launch_bounds__(256) void k_bscatter(const int* __restrict__ src,
                                                  const int* __restrict__ dst,
                                                  int* __restrict__ bcur,
                                                  int2* __restrict__ pairs, int E, int NB) {
    __shared__ int sh[512];
    __shared__ int sbase[512];
    int t = threadIdx.x;
    sh[t] = 0; sh[t + 256] = 0;
    __syncthreads();
    int chunk = (E + NBLK - 1) / NBLK;
    int lo = blockIdx.x * chunk;
    int hi = min(E, lo + chunk);
    for (int e = lo + t; e < hi; e += 256)
        atomicAdd(&sh[dst[e] >> BSH], 1);
    __syncthreads();
    for (int i = t; i < NB; i += 256) {
        int c = sh[i];
        sbase[i] = c ? atomicAdd(&bcur[i], c) : 0;
    }
    __syncthreads();
    for (int i = t; i < NB; i += 256) sh[i] = sbase[i];
    __syncthreads();
    for (int e = lo + t; e < hi; e += 256) {
        int d = dst[e];
        int pos = atomicAdd(&sh[d >> BSH], 1);     // LDS atomic
        pairs[pos] = make_int2(d, src[e]);
    }
}

// ============ pass D: per-bucket exact CSR + offsets + dinv ============

__global__ __launch_bounds__(256) void k_bcsr(const int2* __restrict__ pairs,
                                              const int* __restrict__ bbase,
                                              int* __restrict__ offsets,
                                              int* __restrict__ sorted_src,
                                              float* __restrict__ dinv, int N) {
    __shared__ int hist[256];
    __shared__ int tmp[2][256];
    __shared__ int scur[256];
    int b = blockIdx.x;
    int s0 = bbase[b], s1 = bbase[b + 1];
    int t = threadIdx.x;
    hist[t] = 0;
    __syncthreads();
    for (int e = s0 + t; e < s1; e += 256)
        atomicAdd(&hist[pairs[e].x & 255], 1);     // LDS atomic
    __syncthreads();
    int v = hist[t];
    tmp[0][t] = v;
    __syncthreads();
    int sb = 0;
    for (int d = 1; d < 256; d <<= 1) {
        int val = tmp[sb][t] + ((t >= d) ? tmp[sb][t - d] : 0);
        tmp[sb ^ 1][t] = val;
        sb ^= 1;
        __syncthreads();
    }
    int gbase = s0 + (tmp[sb][t] - v);
    scur[t] = gbase;
    int d = (b << BSH) + t;
    if (d < N) { offsets[d] = gbase; dinv[d] = rsqrtf((float)v + 1.0f); }
    __syncthreads();
    for (int e = s0 + t; e < s1; e += 256) {
        int2 pr = pairs[e];
        int pos = atomicAdd(&scur[pr.x & 255], 1); // LDS atomic
        sorted_src[pos] = pr.y;
    }
}

// ============ GEMM via MFMA, W cast fused into LDS staging ============
// g[i][j] = bf16( dinv[i] * sum_k x[i][k]*W[j][k] )

__global__ __launch_bounds__(256) void k_gemm(const float* __restrict__ x,
                                              const float* __restrict__ W,
                                              const float* __restrict__ dinv,
                                              unsigned short* __restrict__ g, int n) {
    __shared__ unsigned short wb[128][136];
    const int tid = threadIdx.x;

    // stage W fp32 -> bf16 directly into LDS (castW dispatch eliminated)
    for (int chunk = tid; chunk < 2048; chunk += 256) {
        int nrow = chunk >> 4, k8 = (chunk & 15) << 3;
        const float* wp = W + nrow * 128 + k8;
        float4 w0 = *(const float4*)wp;
        float4 w1 = *(const float4*)(wp + 4);
        union { unsigned short u[8]; uint4 q; } pk;
        pk.u[0] = f2bf(w0.x); pk.u[1] = f2bf(w0.y); pk.u[2] = f2bf(w0.z); pk.u[3] = f2bf(w0.w);
        pk.u[4] = f2bf(w1.x); pk.u[5] = f2bf(w1.y); pk.u[6] = f2bf(w1.z); pk.u[7] = f2bf(w1.w);
        *(uint4*)&wb[nrow][k8] = pk.q;
    }
    __syncthreads();

    const int lane = tid & 63;
    const int wid  = tid >> 6;
    const int l15  = lane & 15;
    const int quad = lane >> 4;
    const int row  = blockIdx.x * 64 + wid * 16 + l15;
    const int rowc = (row < n) ? row : (n - 1);

    f32x4 acc[8];
    #pragma unroll
    for (int t = 0; t < 8; ++t) acc[t] = (f32x4){0.f, 0.f, 0.f, 0.f};

    #pragma unroll
    for (int ks = 0; ks < 4; ++ks) {
        const int kb = ks * 32 + quad * 8;
        float4 a0 = *(const float4*)(x + (long)rowc * 128 + kb);
        float4 a1 = *(const float4*)(x + (long)rowc * 128 + kb + 4);
        union { unsigned short u[8]; short8 v; } af;
        af.u[0] = f2bf(a0.x); af.u[1] = f2bf(a0.y); af.u[2] = f2bf(a0.z); af.u[3] = f2bf(a0.w);
        af.u[4] = f2bf(a1.x); af.u[5] = f2bf(a1.y); af.u[6] = f2bf(a1.z); af.u[7] = f2bf(a1.w);
        #pragma unroll
        for (int t = 0; t < 8; ++t) {
            short8 bf = *(const short8*)&wb[t * 16 + l15][kb];
            acc[t] = __builtin_amdgcn_mfma_f32_16x16x32_bf16(af.v, bf, acc[t], 0, 0, 0);
        }
    }

    int   orow[4];
    float dv[4];
    #pragma unroll
    for (int r = 0; r < 4; ++r) {
        orow[r] = blockIdx.x * 64 + wid * 16 + quad * 4 + r;
        dv[r]   = (orow[r] < n) ? dinv[orow[r]] : 0.f;
    }
    #pragma unroll
    for (int t = 0; t < 8; ++t) {
        int col = t * 16 + l15;
        #pragma unroll
        for (int r = 0; r < 4; ++r) {
            if (orow[r] < n)
                g[(long)orow[r] * 128 + col] = f2bf(acc[t][r] * dv[r]);
        }
    }
}

// ============ CSR aggregate: out[d] = dinv[d]*(g[d] + sum g[src]) + b ============
// 32 lanes per dst; 16/4/1 unroll ladder -> up to 16 outstanding 8B gathers.

__global__ __launch_bounds__(256) void k_aggregate(const int* __restrict__ sorted_src,
                                                   const int* __restrict__ offsets,
                                                   const unsigned short* __restrict__ g,
                                                   const float* __restrict__ dinv,
                                                   const float* __restrict__ b,
                                                   float* __restrict__ out, int n) {
    int d = blockIdx.x * (TPB / 32) + (threadIdx.x >> 5);
    if (d >= n) return;
    int c = (threadIdx.x & 31) << 2;

    int s0 = offsets[d];
    int s1 = offsets[d + 1];

    float4 acc = make_float4(0.f, 0.f, 0.f, 0.f);
    auto addrow = [&](int r) {
        uint2 p = *(const uint2*)(g + (long)r * 128 + c);
        acc.x += bflo(p.x); acc.y += bfhi(p.x);
        acc.z += bflo(p.y); acc.w += bfhi(p.y);
    };

    addrow(d);  // self-loop
    int e = s0;
    for (; e + 16 <= s1; e += 16) {
        int a[16];
        #pragma unroll
        for (int j = 0; j < 16; ++j) a[j] = sorted_src[e + j];
        #pragma unroll
        for (int j = 0; j < 16; ++j) addrow(a[j]);
    }
    for (; e + 4 <= s1; e += 4) {
        int a[4];
        #pragma unroll
        for (int j = 0; j < 4; ++j) a[j] = sorted_src[e + j];
        #pragma unroll
        for (int j = 0; j < 4; ++j) addrow(a[j]);
    }
    for (; e < s1; ++e) addrow(sorted_src[e]);

    float s = dinv[d];
    float4 bb = *(const float4*)(b + c);
    float4 r = make_float4(acc.x * s + bb.x, acc.y * s + bb.y,
                           acc.z * s + bb.z, acc.w * s + bb.w);
    *(float4*)(out + (long)d * 128 + c) = r;
}

// ============ launch ============

extern "C" void kernel_launch(void* const* d_in, const int* in_sizes, int n_in,
                              void* d_out, int out_size, void* d_ws, size_t ws_size,
                              hipStream_t stream) {
    const float* x  = (const float*)d_in[0];
    const int*   ei = (const int*)d_in[1];
    // d_in[2] = edge_attr (unused; GCN edge weight = 1)
    const float* W  = (const float*)d_in[3];
    const float* b  = (const float*)d_in[4];
    float* out = (float*)d_out;

    const int N = in_sizes[0] / 128;
    const int E = in_sizes[1] / 2;
    const int* src = ei;
    const int* dst = ei + E;
    const int NB = (N + 255) >> BSH;   // 391 buckets (<= 512)

    // ---- workspace carve (~46 MB) ----
    char* p = (char*)d_ws;
    auto carve = [&](size_t bytes) { char* q = p; p += (bytes + 255) & ~(size_t)255; return q; };
    int*            blockhist  = (int*)           carve((size_t)NBLK * 512 * 4);  // 512 KB
    int*            bbase      = (int*)           carve(513 * 4);
    int*            bcur       = (int*)           carve(512 * 4);
    int*            offsets    = (int*)           carve((size_t)(N + 1) * 4);
    float*          dinv       = (float*)         carve((size_t)N * 4);
    int2*           pairs      = (int2*)          carve((size_t)E * 8);
    int*            sorted_src = (int*)           carve((size_t)E * 4);
    unsigned short* g          = (unsigned short*)carve((size_t)N * 128 * 2);

    k_bhist   <<<NBLK, TPB, 0, stream>>>(dst, blockhist, E);
    k_bscan   <<<1, 512, 0, stream>>>(blockhist, bbase, bcur, offsets, E, N);
    k_bscatter<<<NBLK, TPB, 0, stream>>>(src, dst, bcur, pairs, E, NB);
    k_bcsr    <<<NB, TPB, 0, stream>>>(pairs, bbase, offsets, sorted_src, dinv, N);

    k_gemm<<<(N + 63) / 64, TPB, 0, stream>>>(x, W, dinv, g, N);

    k_aggregate<<<(N + (TPB / 32) - 1) / (TPB / 32), TPB, 0, stream>>>(
        sorted_src, offsets, g, dinv, b, out, N);
}